// Round 9
// baseline (46.573 us; speedup 1.0000x reference)
//
#include <hip/hip_runtime.h>

typedef float f32x4 __attribute__((ext_vector_type(4)));
typedef int   i32x4 __attribute__((ext_vector_type(4)));
typedef int   i32x8 __attribute__((ext_vector_type(8)));

#define D 128
#define PR 512     // panel rows per side (block tile = 512x512)
#define NBLK 256

// ---------------------------------------------------------------------------
// Single self-contained kernel, no cross-block data flow except final reduce:
//  phase N: block normalizes anc[rp*512..+512) and pos[cg*512..+512) to fp8
//           DIRECTLY into LDS (swizzled slots). 16x redundant across blocks,
//           but input slices are L2/L3-resident (8MB total) - cheap.
//           Diag blocks (cg==rp) also compute exact-f32 diag corrections.
//  phase G: LDS-resident fp8-MX GEMM, af[8] hoisted, 8 col-tiles x 16 MFMA.
//           No global traffic, no staging, no inter-iteration barriers.
//  epilogue: relu-sum partial -> ticket-fused finalize (R8-validated).
// ---------------------------------------------------------------------------
__global__ __launch_bounds__(512, 2) void fused_loss_kernel(
    const float* __restrict__ anc, const float* __restrict__ pos,
    float* __restrict__ partials, float* __restrict__ diagP,
    int* __restrict__ counter, float* __restrict__ out, float invBB) {
  __shared__ __align__(16) unsigned char lds[131072];   // A 64KB | B 64KB
  unsigned char* ldsA = lds;
  unsigned char* ldsB = lds + 65536;

  const int tid = threadIdx.x;
  const int bid = blockIdx.x;
  const int w = tid >> 6, l = tid & 63;
  const int rp = bid & 15;          // A panel: anc rows rp*512..
  const int cg = bid >> 4;          // B panel: pos rows cg*512..

  // ================= phase N: normalize panels into LDS (fp8) ==============
  {
    const int rl = tid >> 4, l16 = tid & 15;   // 32 rows/pass, 16 lanes/row
#pragma unroll
    for (int side = 0; side < 2; ++side) {
      const float* src = side ? pos : anc;
      const int gbase = (side ? cg : rp) * PR;
      unsigned char* dst = side ? ldsB : ldsA;
      for (int p = 0; p < 16; ++p) {
        const int r = p * 32 + rl;             // 0..511
        const float* rowp = src + (size_t)(gbase + r) * D + l16 * 8;
        float4 v0 = *(const float4*)rowp, v1 = *(const float4*)(rowp + 4);
        float vv[8] = {v0.x, v0.y, v0.z, v0.w, v1.x, v1.y, v1.z, v1.w};
        float ss = 0.f;
#pragma unroll
        for (int k = 0; k < 8; ++k) ss += vv[k] * vv[k];
#pragma unroll
        for (int off = 1; off < 16; off <<= 1) ss += __shfl_xor(ss, off);
        const float sc = 1.f / fmaxf(sqrtf(ss), 1e-8f);
        float nv[8];
#pragma unroll
        for (int k = 0; k < 8; ++k) nv[k] = vv[k] * sc;
        int w0 = __builtin_amdgcn_cvt_pk_fp8_f32(nv[0], nv[1], 0, false);
        w0 = __builtin_amdgcn_cvt_pk_fp8_f32(nv[2], nv[3], w0, true);
        int w1 = __builtin_amdgcn_cvt_pk_fp8_f32(nv[4], nv[5], 0, false);
        w1 = __builtin_amdgcn_cvt_pk_fp8_f32(nv[6], nv[7], w1, true);
        // swizzled slot store (matches phase-G read: slot ^ (r&7))
        const int sp = ((l16 >> 1) ^ (r & 7));
        *(int2*)(dst + r * 128 + sp * 16 + (l16 & 1) * 8) = make_int2(w0, w1);
      }
    }

    // ---- diag blocks: exact-f32 corrections for rows rp*512..+512
    if (cg == rp) {
      float dwave = 0.f;
      for (int p = 0; p < 16; ++p) {
        const int r = p * 32 + rl;
        const float* ar = anc + (size_t)(rp * PR + r) * D + l16 * 8;
        const float* prw = pos + (size_t)(rp * PR + r) * D + l16 * 8;
        float4 a0 = *(const float4*)ar, a1 = *(const float4*)(ar + 4);
        float4 p0 = *(const float4*)prw, p1 = *(const float4*)(prw + 4);
        float av[8] = {a0.x, a0.y, a0.z, a0.w, a1.x, a1.y, a1.z, a1.w};
        float pv[8] = {p0.x, p0.y, p0.z, p0.w, p1.x, p1.y, p1.z, p1.w};
        float ssa = 0.f, ssp = 0.f, raw = 0.f;
#pragma unroll
        for (int k = 0; k < 8; ++k) {
          ssa += av[k] * av[k];
          ssp += pv[k] * pv[k];
          raw += av[k] * pv[k];
        }
#pragma unroll
        for (int off = 1; off < 16; off <<= 1) {
          ssa += __shfl_xor(ssa, off);
          ssp += __shfl_xor(ssp, off);
          raw += __shfl_xor(raw, off);
        }
        const float sa = 1.f / fmaxf(sqrtf(ssa), 1e-8f);
        const float sp2 = 1.f / fmaxf(sqrtf(ssp), 1e-8f);
        const float cosv = raw * sa * sp2;
        float c = 1.f - cosv - fmaxf(cosv, 0.f);
        if (l16 != 0) c = 0.f;
        dwave += c;
      }
#pragma unroll
      for (int off = 1; off < 64; off <<= 1) dwave += __shfl_xor(dwave, off);
      if (l == 0)
        __hip_atomic_store(&diagP[rp * 8 + w], dwave, __ATOMIC_RELAXED,
                           __HIP_MEMORY_SCOPE_AGENT);
    }
  }
  __syncthreads();

  // ================= phase G: LDS-resident fp8-MX GEMM =====================
  const int r16 = l & 15, kg = l >> 4;
  const int wrow = w >> 1, wcol = w & 1;   // 4x2 waves; wave tile 128r x 32c/ct

  i32x8 af[8];                             // A fragments, hoisted once
#pragma unroll
  for (int m = 0; m < 8; ++m) {
    const int r = wrow * 128 + m * 16 + r16;
    const unsigned char* base = ldsA + r * 128;
    i32x4 lo = *(const i32x4*)(base + (((2 * kg) ^ (r & 7)) * 16));
    i32x4 hi = *(const i32x4*)(base + (((2 * kg + 1) ^ (r & 7)) * 16));
    af[m] = __builtin_shufflevector(lo, hi, 0, 1, 2, 3, 4, 5, 6, 7);
  }

  float s0 = 0.f, s1 = 0.f, s2 = 0.f, s3 = 0.f;
#pragma unroll
  for (int ct = 0; ct < 8; ++ct) {         // 8 col tiles of 64
    i32x8 bfr[2];
#pragma unroll
    for (int n = 0; n < 2; ++n) {
      const int r = ct * 64 + wcol * 32 + n * 16 + r16;
      const unsigned char* base = ldsB + r * 128;
      i32x4 lo = *(const i32x4*)(base + (((2 * kg) ^ (r & 7)) * 16));
      i32x4 hi = *(const i32x4*)(base + (((2 * kg + 1) ^ (r & 7)) * 16));
      bfr[n] = __builtin_shufflevector(lo, hi, 0, 1, 2, 3, 4, 5, 6, 7);
    }
    f32x4 acc[8][2] = {};
    __builtin_amdgcn_s_setprio(1);
#pragma unroll
    for (int m = 0; m < 8; ++m)
#pragma unroll
      for (int n = 0; n < 2; ++n)
        acc[m][n] = __builtin_amdgcn_mfma_scale_f32_16x16x128_f8f6f4(
            af[m], bfr[n], acc[m][n], 0, 0,   // cbsz=fp8, blgp=fp8
            0, 0x7f7f7f7f, 0, 0x7f7f7f7f);    // scales = 1.0
    __builtin_amdgcn_s_setprio(0);
#pragma unroll
    for (int m = 0; m < 8; ++m)
#pragma unroll
      for (int n = 0; n < 2; ++n) {
        s0 += fmaxf(acc[m][n][0], 0.f);
        s1 += fmaxf(acc[m][n][1], 0.f);
        s2 += fmaxf(acc[m][n][2], 0.f);
        s3 += fmaxf(acc[m][n][3], 0.f);
      }
  }

  // ================= epilogue: block partial + ticket finalize =============
  __syncthreads();                  // all LDS reads done -> reuse lds as scratch
  float* wpart = (float*)lds;
  int* lastFlag = (int*)(lds + 64);

  float s = (s0 + s1) + (s2 + s3);
#pragma unroll
  for (int off = 32; off >= 1; off >>= 1) s += __shfl_xor(s, off);
  if (l == 0) wpart[w] = s;
  __syncthreads();
  if (tid == 0) {
    float b = 0.f;
#pragma unroll
    for (int i = 0; i < 8; ++i) b += wpart[i];
    __hip_atomic_store(&partials[bid], b, __ATOMIC_RELAXED,
                       __HIP_MEMORY_SCOPE_AGENT);
    __threadfence();
    const int ticket = __hip_atomic_fetch_add(counter, 1, __ATOMIC_ACQ_REL,
                                              __HIP_MEMORY_SCOPE_AGENT);
    lastFlag[0] = (ticket == NBLK - 1) ? 1 : 0;
  }
  __syncthreads();

  if (lastFlag[0]) {
    __threadfence();
    float v = 0.f;
    if (tid < NBLK)
      v = __hip_atomic_load(&partials[tid], __ATOMIC_RELAXED,
                            __HIP_MEMORY_SCOPE_AGENT);
    if (tid < 128)
      v += __hip_atomic_load(&diagP[tid], __ATOMIC_RELAXED,
                             __HIP_MEMORY_SCOPE_AGENT);
#pragma unroll
    for (int off = 32; off >= 1; off >>= 1) v += __shfl_xor(v, off);
    if (l == 0) wpart[w] = v;
    __syncthreads();
    if (tid == 0) {
      float tot = 0.f;
#pragma unroll
      for (int i = 0; i < 8; ++i) tot += wpart[i];
      out[0] = tot * invBB;
    }
  }
}

extern "C" void kernel_launch(void* const* d_in, const int* in_sizes, int n_in,
                              void* d_out, int out_size, void* d_ws, size_t ws_size,
                              hipStream_t stream) {
  const float* pos = (const float*)d_in[0];  // hid_positive
  const float* anc = (const float*)d_in[1];  // hid_anchor
  const int B = in_sizes[0] / D;             // 8192
  (void)B;

  char* ws = (char*)d_ws;
  float* partials = (float*)ws;              // 256 f32
  float* diagP = partials + NBLK;            // 128 f32 (16 diag blocks x 8 waves)
  int* counter = (int*)(diagP + 128);

  const float invBB = 1.0f / (8192.0f * 8192.0f);

  hipMemsetAsync(counter, 0, 4, stream);
  fused_loss_kernel<<<NBLK, 512, 0, stream>>>(pos ? anc : anc, pos, partials,
                                              diagP, counter, (float*)d_out,
                                              invBB);
}